// Round 4
// baseline (19.177 us; speedup 1.0000x reference)
//
#include <hip/hip_runtime.h>

#define BQ  8     // batch of queries
#define DIM 128   // embedding dim

// One 32-lane group per FOUR contiguous candidate entities per iteration;
// lane holds float4 of 4 dims. 256 threads/block = 8 groups.
// Depth-1 pipeline: 4 rows (2KB contiguous) per group in flight while the
// previous 4 are computed. Two sequential 16-acc selection-reduce trees;
// float4 stores (4 adjacent columns) from lanes lane&3==0.
__global__ __launch_bounds__(256) void transe_score_kernel(
    const int*   __restrict__ head,
    const int*   __restrict__ relation,
    const int*   __restrict__ tail,
    const float* __restrict__ emb_entity,
    const float* __restrict__ emb_relation,
    const float* __restrict__ bias_head,
    const float* __restrict__ bias_tail,
    float*       __restrict__ out,
    int E)
{
    __shared__ float pred[BQ][DIM];
    __shared__ float bh_s[BQ];

    const int t = threadIdx.x;

    for (int i = t; i < BQ * DIM; i += 256) {
        int b = i >> 7, d = i & 127;
        pred[b][d] = emb_entity[(size_t)head[b] * DIM + d]
                   + emb_relation[(size_t)relation[b] * DIM + d];
    }
    if (t < BQ) bh_s[t] = bias_head[head[t]];
    __syncthreads();

    const int lane = t & 31;
    const int grp  = t >> 5;
    const int lq   = lane << 2;

    // ||t-p||^2 = ||t||^2 - 2 t.p + ||p||^2 ; hoist -2p and per-lane sum(p^2)
    float4 pm2[BQ];
    float  pq[BQ];
    #pragma unroll
    for (int b = 0; b < BQ; ++b) {
        float4 p = *reinterpret_cast<const float4*>(&pred[b][lq]);
        pm2[b] = make_float4(-2.f*p.x, -2.f*p.y, -2.f*p.z, -2.f*p.w);
        pq[b]  = p.x*p.x + p.y*p.y + p.z*p.z + p.w*p.w;
    }

    const int   myB   = (lane >> 2) & 7;     // from tree selection bits 2,3,4
    const bool  wlane = (lane & 3) == 0;     // 8 writer lanes, one per query
    const float myBh  = bh_s[myB];

    const int estep = gridDim.x * 32;        // entities per round (8 grp x 4)
    const int elast = ((E - 4) >> 2) << 2;   // last aligned quad base
    int e = (blockIdx.x * 8 + grp) * 4;
    if (e >= E) return;

    // ---- pipeline prologue ----
    int4 ti0 = *(const int4*)&tail[e];
    int  en  = e + estep;
    int4 ti1 = *(const int4*)&tail[en <= elast ? en : elast];

    float bt_x = bias_tail[ti0.x], bt_y = bias_tail[ti0.y];
    float bt_z = bias_tail[ti0.z], bt_w = bias_tail[ti0.w];
    float4 va = *(const float4*)&emb_entity[(size_t)ti0.x * DIM + lq];
    float4 vb = *(const float4*)&emb_entity[(size_t)ti0.y * DIM + lq];
    float4 vc = *(const float4*)&emb_entity[(size_t)ti0.z * DIM + lq];
    float4 vd = *(const float4*)&emb_entity[(size_t)ti0.w * DIM + lq];

    // Selection-reduce: collapse 16 accs -> 2 (stages 16,8,4), then plain
    // xor2/xor1 finishes so ALL lanes hold both results for b=(lane>>2)&7.
#define TREE(ACC, R0, R1)                                                   \
    {   bool hi = (lane & 16) != 0;                                         \
        _Pragma("unroll")                                                   \
        for (int i = 0; i < 8; ++i) {                                       \
            float send = hi ? ACC[i]     : ACC[i + 8];                      \
            float keep = hi ? ACC[i + 8] : ACC[i];                          \
            ACC[i] = keep + __shfl_xor(send, 16, 32);                       \
        } }                                                                 \
    {   bool hi = (lane & 8) != 0;                                          \
        _Pragma("unroll")                                                   \
        for (int i = 0; i < 4; ++i) {                                       \
            float send = hi ? ACC[i]     : ACC[i + 4];                      \
            float keep = hi ? ACC[i + 4] : ACC[i];                          \
            ACC[i] = keep + __shfl_xor(send, 8, 32);                        \
        } }                                                                 \
    {   bool hi = (lane & 4) != 0;                                          \
        _Pragma("unroll")                                                   \
        for (int i = 0; i < 2; ++i) {                                       \
            float send = hi ? ACC[i]     : ACC[i + 2];                      \
            float keep = hi ? ACC[i + 2] : ACC[i];                          \
            ACC[i] = keep + __shfl_xor(send, 4, 32);                        \
        } }                                                                 \
    ACC[0] += __shfl_xor(ACC[0], 2, 32);                                    \
    ACC[1] += __shfl_xor(ACC[1], 2, 32);                                    \
    ACC[0] += __shfl_xor(ACC[0], 1, 32);                                    \
    ACC[1] += __shfl_xor(ACC[1], 1, 32);                                    \
    R0 = ACC[0]; R1 = ACC[1];

    while (true) {
        // ---- prefetch next quad (independent of current compute) ----
        int  en2 = en + estep;
        int4 ti2 = *(const int4*)&tail[en2 <= elast ? en2 : elast];
        float btn_x = bias_tail[ti1.x], btn_y = bias_tail[ti1.y];
        float btn_z = bias_tail[ti1.z], btn_w = bias_tail[ti1.w];
        float4 wa = *(const float4*)&emb_entity[(size_t)ti1.x * DIM + lq];
        float4 wb = *(const float4*)&emb_entity[(size_t)ti1.y * DIM + lq];
        float4 wc = *(const float4*)&emb_entity[(size_t)ti1.z * DIM + lq];
        float4 wd = *(const float4*)&emb_entity[(size_t)ti1.w * DIM + lq];

        // ---- tree A: entities e, e+1 (rows va, vb) ----
        float rA0, rA1, rB0, rB1;
        {
            float t2a = va.x*va.x + va.y*va.y + va.z*va.z + va.w*va.w;
            float t2b = vb.x*vb.x + vb.y*vb.y + vb.z*vb.z + vb.w*vb.w;
            float acc[16];
            #pragma unroll
            for (int b = 0; b < BQ; ++b) {
                float a = t2a + pq[b];
                a = fmaf(va.x, pm2[b].x, a);
                a = fmaf(va.y, pm2[b].y, a);
                a = fmaf(va.z, pm2[b].z, a);
                a = fmaf(va.w, pm2[b].w, a);
                acc[2*b] = a;
                float c = t2b + pq[b];
                c = fmaf(vb.x, pm2[b].x, c);
                c = fmaf(vb.y, pm2[b].y, c);
                c = fmaf(vb.z, pm2[b].z, c);
                c = fmaf(vb.w, pm2[b].w, c);
                acc[2*b+1] = c;
            }
            TREE(acc, rA0, rA1)
        }
        // ---- tree B: entities e+2, e+3 (rows vc, vd) ----
        {
            float t2a = vc.x*vc.x + vc.y*vc.y + vc.z*vc.z + vc.w*vc.w;
            float t2b = vd.x*vd.x + vd.y*vd.y + vd.z*vd.z + vd.w*vd.w;
            float acc[16];
            #pragma unroll
            for (int b = 0; b < BQ; ++b) {
                float a = t2a + pq[b];
                a = fmaf(vc.x, pm2[b].x, a);
                a = fmaf(vc.y, pm2[b].y, a);
                a = fmaf(vc.z, pm2[b].z, a);
                a = fmaf(vc.w, pm2[b].w, a);
                acc[2*b] = a;
                float c = t2b + pq[b];
                c = fmaf(vd.x, pm2[b].x, c);
                c = fmaf(vd.y, pm2[b].y, c);
                c = fmaf(vd.z, pm2[b].z, c);
                c = fmaf(vd.w, pm2[b].w, c);
                acc[2*b+1] = c;
            }
            TREE(acc, rB0, rB1)
        }

        if (wlane) {
            float4 r;
            r.x = sqrtf(fmaxf(rA0, 0.f)) + myBh + bt_x;
            r.y = sqrtf(fmaxf(rA1, 0.f)) + myBh + bt_y;
            r.z = sqrtf(fmaxf(rB0, 0.f)) + myBh + bt_z;
            r.w = sqrtf(fmaxf(rB1, 0.f)) + myBh + bt_w;
            *reinterpret_cast<float4*>(&out[(size_t)myB * E + e]) = r;
        }

        // ---- rotate pipeline ----
        e = en;
        if (e >= E) break;
        en = en2; ti1 = ti2;
        bt_x = btn_x; bt_y = btn_y; bt_z = btn_z; bt_w = btn_w;
        va = wa; vb = wb; vc = wc; vd = wd;
    }
#undef TREE
}

extern "C" void kernel_launch(void* const* d_in, const int* in_sizes, int n_in,
                              void* d_out, int out_size, void* d_ws, size_t ws_size,
                              hipStream_t stream) {
    const int*   head         = (const int*)  d_in[0];
    const int*   relation     = (const int*)  d_in[1];
    const int*   tail         = (const int*)  d_in[2];
    const float* emb_entity   = (const float*)d_in[3];
    const float* emb_relation = (const float*)d_in[4];
    const float* bias_head    = (const float*)d_in[5];
    const float* bias_tail    = (const float*)d_in[6];
    float* out = (float*)d_out;

    const int E = in_sizes[2];          // 100000, multiple of 4

    // 1024 blocks x 4 waves = 4096 waves (4/SIMD at <=128 VGPR);
    // 8192 groups x 4 entities = 32768 entities per round, ~3 iterations.
    int blocks = 1024;
    int maxb = (E + 31) / 32;
    if (blocks > maxb) blocks = maxb;

    hipLaunchKernelGGL(transe_score_kernel, dim3(blocks), dim3(256), 0, stream,
                       head, relation, tail, emb_entity, emb_relation,
                       bias_head, bias_tail, out, E);
}